// Round 10
// baseline (2039.140 us; speedup 1.0000x reference)
//
#include <hip/hip_runtime.h>
#include <hip/hip_bf16.h>

// Problem constants (from reference)
#define NUME 100000
constexpr int H      = 4;
constexpr int DH     = 32;
constexpr int KNB    = 16;     // neighbors per dst
constexpr int R      = 17;     // relations
constexpr int DIN    = 128;
constexpr int DT     = 32;
constexpr int DINT   = 160;    // DIN + DT
constexpr int N0     = 131072;
constexpr int N1     = 32768;
constexpr int N2     = 4096;
constexpr float LN_EPS = 1e-5f;

typedef unsigned short ushort_t;
typedef ushort_t us4 __attribute__((ext_vector_type(4)));
typedef ushort_t us8 __attribute__((ext_vector_type(8)));
typedef short    s8v __attribute__((ext_vector_type(8)));
typedef float    f32x4 __attribute__((ext_vector_type(4)));

__device__ __forceinline__ float bf2f(ushort_t u) {
    return __uint_as_float(((unsigned int)u) << 16);
}
__device__ __forceinline__ ushort_t f2bf(float f) {   // round-to-nearest-even
    unsigned int x = __float_as_uint(f);
    unsigned int r = x + 0x7fffu + ((x >> 16) & 1u);
    return (ushort_t)(r >> 16);
}
// LDS helpers: us8 value <-> two us4 LDS slots (odd-dword row strides)
__device__ __forceinline__ void st_us8_2(ushort_t* p, us8 v) {
    *(us4*)p       = __builtin_shufflevector(v, v, 0, 1, 2, 3);
    *(us4*)(p + 4) = __builtin_shufflevector(v, v, 4, 5, 6, 7);
}
__device__ __forceinline__ s8v ld_s8v_2(const ushort_t* p) {
    us4 a = *(const us4*)p;
    us4 b = *(const us4*)(p + 4);
    us8 t = __builtin_shufflevector(a, b, 0, 1, 2, 3, 4, 5, 6, 7);
    s8v r;
    __builtin_memcpy(&r, &t, 16);
    return r;
}

// -------------------------------------------------------------------------
// K0: W [R][160][128] f32  ->  wt [R][128][160] bf16 (transposed per rel)
// -------------------------------------------------------------------------
__global__ __launch_bounds__(256) void k_wcast(
    const float* __restrict__ W, ushort_t* __restrict__ wt, int total)
{
    int t = blockIdx.x * blockDim.x + threadIdx.x;
    if (t >= total) return;
    int r   = t / (DINT * DIN);
    int rem = t % (DINT * DIN);
    int k   = rem >> 7;            // 0..159
    int n   = rem & 127;           // 0..127
    wt[(size_t)r * DIN * DINT + (size_t)n * DINT + k] = f2bf(W[t]);
}

// -------------------------------------------------------------------------
// K0b: bsum0[c] = sum_r b0[r][c], bsum1[c] = sum_r b1[r][c]  (1 block)
// -------------------------------------------------------------------------
__global__ __launch_bounds__(256) void k_bsum(
    const float* __restrict__ b0, const float* __restrict__ b1,
    float* __restrict__ bsum01)
{
    int t = threadIdx.x;
    const float* b = (t < 128) ? b0 : b1;
    int c = t & 127;
    float s = 0.f;
    #pragma unroll
    for (int r = 0; r < R; ++r) s += b[r * 128 + c];
    bsum01[t] = s;
}

// -------------------------------------------------------------------------
// K1: [optional relu((x+bsum)/R)] + time-enc + concat + LayerNorm.
// One wave = 2 rows (32 lanes each), float4 loads, 5-round butterfly.
// -------------------------------------------------------------------------
__global__ __launch_bounds__(256) void k_prep(
    const float* __restrict__ srcf,
    const int*   __restrict__ ids,
    const int*   __restrict__ ts_ptr,
    const float* __restrict__ freq,
    const float* __restrict__ phase,
    const float* __restrict__ gamma,
    const float* __restrict__ beta,
    const float* __restrict__ bsum,      // [128], used in mode 0
    ushort_t*    __restrict__ hn,
    int n_rows, int mode)
{
    int wv   = (int)((blockIdx.x * blockDim.x + threadIdx.x) >> 6);
    int lane = threadIdx.x & 63;
    int half = lane >> 5;
    int l5   = lane & 31;
    int row  = wv * 2 + half;
    if (row >= n_rows) return;

    int id = ids[row];
    const float* rp = (mode == 1)
        ? (srcf + (size_t)(id % NUME) * DIN)
        : (srcf + (size_t)row * DIN);

    float4 x = *(const float4*)&rp[l5 * 4];
    if (mode == 0) {
        const float4 bs = *(const float4*)&bsum[l5 * 4];
        x.x = fmaxf((x.x + bs.x) * (1.f / (float)R), 0.f);
        x.y = fmaxf((x.y + bs.y) * (1.f / (float)R), 0.f);
        x.z = fmaxf((x.z + bs.z) * (1.f / (float)R), 0.f);
        x.w = fmaxf((x.w + bs.w) * (1.f / (float)R), 0.f);
    }

    int   ts = ts_ptr[0];
    float t  = (float)(ts - id / NUME);
    float p  = cosf(t * freq[l5] + phase[l5]);

    float s  = x.x + x.y + x.z + x.w + p;
    float sq = x.x*x.x + x.y*x.y + x.z*x.z + x.w*x.w + p*p;
    #pragma unroll
    for (int m = 1; m < 32; m <<= 1) {
        s  += __shfl_xor(s,  m);
        sq += __shfl_xor(sq, m);
    }
    float mu   = s / (float)DINT;
    float var  = sq / (float)DINT - mu * mu;
    float rstd = rsqrtf(var + LN_EPS);

    size_t base = (size_t)row * DINT;
    us4 pk;
    pk[0] = f2bf((x.x - mu) * rstd * gamma[l5*4+0] + beta[l5*4+0]);
    pk[1] = f2bf((x.y - mu) * rstd * gamma[l5*4+1] + beta[l5*4+1]);
    pk[2] = f2bf((x.z - mu) * rstd * gamma[l5*4+2] + beta[l5*4+2]);
    pk[3] = f2bf((x.w - mu) * rstd * gamma[l5*4+3] + beta[l5*4+3]);
    *(us4*)&hn[base + l5*4] = pk;
    hn[base + 128 + l5] = f2bf((p - mu) * rstd * gamma[128 + l5] + beta[128 + l5]);
}

// -------------------------------------------------------------------------
// K2: MFMA GEMM + fused attention-dot epilogue (B-resident, dbuf A).
// r = blockIdx.y is the group-local relation. Odd-dword LDS strides
// (As 42, Bs 170 ushorts) + us4-pair access: staging writes drop from
// 8-way to <=2-way bank conflicts.
// -------------------------------------------------------------------------
__global__ __launch_bounds__(256) void k_gemm(
    const ushort_t* __restrict__ A,      // [M,160] bf16
    const ushort_t* __restrict__ BtB,    // [gsz,128,160] bf16 base
    const float*    __restrict__ alB,    // [gsz,128] base
    const float*    __restrict__ arB,
    ushort_t*       __restrict__ CB,     // [gsz,M,128] base
    float*          __restrict__ elB,    // [gsz,M,4] base
    float*          __restrict__ erB,    // [gsz,ndst,4] base
    int ndst, int M)
{
    __shared__ ushort_t Bs[128][170];     // stride 340B = 85 dw (odd)
    __shared__ ushort_t As[2][128][42];   // stride 84B = 21 dw (odd)

    int r = blockIdx.y;
    const ushort_t* Bt = BtB + (size_t)r * DIN * DINT;
    const float*    al = alB + (size_t)r * DIN;
    const float*    ar = arB + (size_t)r * DIN;
    ushort_t*       C  = CB  + (size_t)r * M * DIN;
    float*          el = elB + (size_t)r * M * 4;
    float*          er = erB + (size_t)r * ndst * 4;

    int tid  = threadIdx.x;
    int lane = tid & 63;
    int wave = tid >> 6;
    int wr   = wave >> 1;
    int wc   = wave & 1;
    int row0 = blockIdx.x * 128;

    // ---- prologue: stage full Bs + As chunk 0
    {
        int bm  = tid >> 1;
        int bko = (tid & 1) * 80;
        #pragma unroll
        for (int g = 0; g < 10; ++g) {
            us8 t = *(const us8*)&Bt[(size_t)bm * DINT + bko + g * 8];
            st_us8_2(&Bs[bm][bko + g * 8], t);
        }
        #pragma unroll
        for (int j = 0; j < 2; ++j) {
            int f  = tid + j * 256;
            int m  = f >> 2;
            int ko = (f & 3) * 8;
            us8 t = *(const us8*)&A[(size_t)(row0 + m) * DINT + ko];
            st_us8_2(&As[0][m][ko], t);
        }
    }
    __syncthreads();

    s8v breg[5][4];
    #pragma unroll
    for (int kk = 0; kk < 5; ++kk)
        #pragma unroll
        for (int j = 0; j < 4; ++j)
            breg[kk][j] = ld_s8v_2(&Bs[wc*64 + j*16 + (lane & 15)]
                                      [kk*32 + (lane >> 4) * 8]);

    f32x4 acc[4][4];
    #pragma unroll
    for (int i = 0; i < 4; ++i)
        #pragma unroll
        for (int j = 0; j < 4; ++j) acc[i][j] = (f32x4){0.f, 0.f, 0.f, 0.f};

    #pragma unroll
    for (int kc = 0; kc < 5; ++kc) {
        us8 pa[2];
        int m0 = 0, ko0 = 0, m1 = 0, ko1 = 0;
        if (kc < 4) {
            int f0 = tid;
            m0  = f0 >> 2; ko0 = (f0 & 3) * 8;
            pa[0] = *(const us8*)&A[(size_t)(row0 + m0) * DINT + (kc + 1) * 32 + ko0];
            int f1 = tid + 256;
            m1  = f1 >> 2; ko1 = (f1 & 3) * 8;
            pa[1] = *(const us8*)&A[(size_t)(row0 + m1) * DINT + (kc + 1) * 32 + ko1];
        }

        s8v af[4];
        #pragma unroll
        for (int i = 0; i < 4; ++i)
            af[i] = ld_s8v_2(&As[kc & 1][wr*64 + i*16 + (lane & 15)]
                                        [(lane >> 4) * 8]);
        #pragma unroll
        for (int i = 0; i < 4; ++i)
            #pragma unroll
            for (int j = 0; j < 4; ++j)
                acc[i][j] = __builtin_amdgcn_mfma_f32_16x16x32_bf16(
                                af[i], breg[kc][j], acc[i][j], 0, 0, 0);

        if (kc < 4) {
            st_us8_2(&As[(kc + 1) & 1][m0][ko0], pa[0]);
            st_us8_2(&As[(kc + 1) & 1][m1][ko1], pa[1]);
        }
        __syncthreads();
    }

    // ---- C write-out
    #pragma unroll
    for (int i = 0; i < 4; ++i) {
        #pragma unroll
        for (int j = 0; j < 4; ++j) {
            int col  = wc*64 + j*16 + (lane & 15);
            int rowb = row0 + wr*64 + i*16 + ((lane >> 4) << 2);
            #pragma unroll
            for (int q = 0; q < 4; ++q)
                C[(size_t)(rowb + q) * DIN + col] = f2bf(acc[i][j][q]);
        }
    }

    // ---- fused el/er epilogue
    float alv[4], arv[4];
    #pragma unroll
    for (int j = 0; j < 4; ++j) {
        int c = wc*64 + j*16 + (lane & 15);
        alv[j] = al[c];
        arv[j] = ar[c];
    }
    int b0 = lane & 1;
    int b1 = (lane >> 1) & 1;
    #pragma unroll
    for (int i = 0; i < 4; ++i) {
        #pragma unroll
        for (int q = 0; q < 4; ++q) {
            float pl0 = acc[i][0][q]*alv[0] + acc[i][1][q]*alv[1];
            float pl1 = acc[i][2][q]*alv[2] + acc[i][3][q]*alv[3];
            float pr0 = acc[i][0][q]*arv[0] + acc[i][1][q]*arv[1];
            float pr1 = acc[i][2][q]*arv[2] + acc[i][3][q]*arv[3];
            float t;
            t = __shfl_xor(b0 ? pl0 : pl1, 1);
            float vA = (b0 ? pl1 : pl0) + t;
            t = __shfl_xor(b0 ? pr0 : pr1, 1);
            float vB = (b0 ? pr1 : pr0) + t;
            t = __shfl_xor(b1 ? vA : vB, 2);
            float vC = (b1 ? vB : vA) + t;
            vC += __shfl_xor(vC, 4);
            vC += __shfl_xor(vC, 8);
            if ((lane & 12) == 0) {
                int row = row0 + wr*64 + i*16 + ((lane >> 4) << 2) + q;
                int h   = 2*wc + b0;
                if (!b1) {
                    el[(size_t)row * 4 + h] = vC;
                } else if (row < ndst) {
                    er[(size_t)row * 4 + h] = vC;
                }
            }
        }
    }
}

// -------------------------------------------------------------------------
// K3: grouped edge softmax + aggregate. One wave per dst; loops the group's
// gsz relations with REGISTER accumulation; touches accg once.
// init=1: overwrite accg (first group), else RMW.
// -------------------------------------------------------------------------
__global__ __launch_bounds__(256) void k_agg_grp(
    const ushort_t* __restrict__ projB,  // [gsz,nsrc,128] bf16
    const int*      __restrict__ idxB,   // [gsz,ndst,16]
    const float*    __restrict__ elB,    // [gsz,nsrc,4]
    const float*    __restrict__ erB,    // [gsz,ndst,4]
    float*          __restrict__ accg,   // [ndst,128] f32
    int ndst, int nsrc, int gsz, int init)
{
    int wid  = (int)((blockIdx.x * blockDim.x + threadIdx.x) >> 6);
    if (wid >= ndst) return;
    int l    = threadIdx.x & 63;
    int rsub = l >> 4;
    int fg   = l & 15;

    const ushort_t* proj = projB;
    const int*      idx  = idxB;
    const float*    el   = elB;
    const float*    er   = erB;

    float vacc[8];
    #pragma unroll
    for (int t = 0; t < 8; ++t) vacc[t] = 0.f;

    for (int gr = 0; gr < gsz; ++gr) {
        int jv = idx[(size_t)wid * KNB + (l & 15)];

        int j2[4];
        us8 v[4];
        #pragma unroll
        for (int kk = 0; kk < 4; ++kk) j2[kk] = __shfl(jv, 4*kk + rsub);
        #pragma unroll
        for (int kk = 0; kk < 4; ++kk)
            v[kk] = *(const us8*)&proj[(size_t)j2[kk] * DIN + fg * 8];

        int   jk = __shfl(jv, l >> 2);
        float e  = el[(size_t)jk * 4 + (l & 3)] + er[(size_t)wid * 4 + (l & 3)];
        e = e > 0.f ? e : 0.2f * e;
        float mx = e;
        #pragma unroll
        for (int m = 4; m < 64; m <<= 1) mx = fmaxf(mx, __shfl_xor(mx, m));
        float p = __expf(e - mx);
        float s = p;
        #pragma unroll
        for (int m = 4; m < 64; m <<= 1) s += __shfl_xor(s, m);
        float a = p / s;

        #pragma unroll
        for (int kk = 0; kk < 4; ++kk) {
            float ak = __shfl(a, 16*kk + 4*rsub + (fg >> 2));
            #pragma unroll
            for (int t = 0; t < 8; ++t) vacc[t] = fmaf(ak, bf2f(v[kk][t]), vacc[t]);
        }

        proj += (size_t)nsrc * DIN;
        idx  += (size_t)ndst * KNB;
        el   += (size_t)nsrc * 4;
        er   += (size_t)ndst * 4;
    }

    #pragma unroll
    for (int t = 0; t < 8; ++t) {
        vacc[t] += __shfl_xor(vacc[t], 16);
        vacc[t] += __shfl_xor(vacc[t], 32);
    }
    if (l < 16) {
        float* ap = accg + (size_t)wid * DIN + l * 8;
        if (init) {
            #pragma unroll
            for (int t = 0; t < 8; ++t) ap[t] = vacc[t];
        } else {
            #pragma unroll
            for (int t = 0; t < 8; ++t) ap[t] += vacc[t];
        }
    }
}

// -------------------------------------------------------------------------
// K5: out[t] = relu((acc[root[t/128]][t%128] + bsum1[t%128]) / R)
// -------------------------------------------------------------------------
__global__ __launch_bounds__(256) void k_root(
    const float* __restrict__ acc, const int* __restrict__ root,
    const float* __restrict__ bsum1, float* __restrict__ out, int n)
{
    int t = blockIdx.x * blockDim.x + threadIdx.x;
    if (t < n) {
        float x = acc[(size_t)root[t >> 7] * DIN + (t & 127)] + bsum1[t & 127];
        out[t] = fmaxf(x * (1.f / (float)R), 0.f);
    }
}

// -------------------------------------------------------------------------
extern "C" void kernel_launch(void* const* d_in, const int* in_sizes, int n_in,
                              void* d_out, int out_size, void* d_ws, size_t ws_size,
                              hipStream_t stream)
{
    const float* emb    = (const float*)d_in[0];
    const float* freq   = (const float*)d_in[1];
    const float* phase  = (const float*)d_in[2];
    const float* gamma0 = (const float*)d_in[3];
    const float* beta0  = (const float*)d_in[4];
    const float* W0     = (const float*)d_in[5];
    const float* al0    = (const float*)d_in[6];
    const float* ar0    = (const float*)d_in[7];
    const float* b0     = (const float*)d_in[8];
    const float* gamma1 = (const float*)d_in[9];
    const float* beta1  = (const float*)d_in[10];
    const float* W1     = (const float*)d_in[11];
    const float* al1    = (const float*)d_in[12];
    const float* ar1    = (const float*)d_in[13];
    const float* b1     = (const float*)d_in[14];
    const int* src_ids0 = (const int*)d_in[15];
    const int* src_idx0 = (const int*)d_in[16];
    const int* src_ids1 = (const int*)d_in[17];
    const int* src_idx1 = (const int*)d_in[18];
    const int* root     = (const int*)d_in[19];
    const int* ts       = (const int*)d_in[20];
    float* out = (float*)d_out;

    // ---- workspace carve (byte cursor, 256B aligned), ~217 MB
    char* cur = (char*)d_ws;
    auto carve = [&](size_t bytes) {
        char* p = cur;
        cur += (bytes + 255) & ~(size_t)255;
        return (void*)p;
    };
    ushort_t* hn    = (ushort_t*)carve((size_t)N0 * DINT * 2);
    float*    acc   = (float*)carve((size_t)N1 * DIN * 4);
    ushort_t* wt0   = (ushort_t*)carve((size_t)R * DIN * DINT * 2);
    ushort_t* wt1   = (ushort_t*)carve((size_t)R * DIN * DINT * 2);
    float*    bsum  = (float*)carve(256 * 4);
    ushort_t* projg = (ushort_t*)carve((size_t)4 * N0 * DIN * 2);  // group proj
    float*    elg   = (float*)carve((size_t)4 * N0 * 4 * 4);
    float*    erg   = (float*)carve((size_t)4 * N1 * 4 * 4);

    const int WTOT = R * DINT * DIN;
    const int gstart[6] = {0, 4, 8, 12, 16, 17};

    // ---- constants / weights prep
    k_bsum<<<1, 256, 0, stream>>>(b0, b1, bsum);
    k_wcast<<<(WTOT + 255) / 256, 256, 0, stream>>>(W0, wt0, WTOT);
    k_wcast<<<(WTOT + 255) / 256, 256, 0, stream>>>(W1, wt1, WTOT);

    // ---------------- layer 0 (grouped relations) ----------------
    k_prep<<<N0 / 8, 256, 0, stream>>>(emb, src_ids0, ts, freq, phase,
                                       gamma0, beta0, bsum, hn, N0, 1);
    for (int g = 0; g < 5; ++g) {
        int g0 = gstart[g], gsz = gstart[g + 1] - g0;
        k_gemm<<<dim3(N0 / 128, gsz), 256, 0, stream>>>(
            hn, wt0 + (size_t)g0 * DIN * DINT, al0 + g0 * 128, ar0 + g0 * 128,
            projg, elg, erg, N1, N0);
        k_agg_grp<<<N1 / 4, 256, 0, stream>>>(
            projg, src_idx0 + (size_t)g0 * N1 * KNB, elg, erg,
            acc, N1, N0, gsz, g == 0);
    }

    // ---------------- layer 1 (grouped relations) ----------------
    k_prep<<<N1 / 8, 256, 0, stream>>>(acc, src_ids1, ts, freq, phase,
                                       gamma1, beta1, bsum, hn, N1, 0);
    for (int g = 0; g < 5; ++g) {
        int g0 = gstart[g], gsz = gstart[g + 1] - g0;
        k_gemm<<<dim3(N1 / 128, gsz), 256, 0, stream>>>(
            hn, wt1 + (size_t)g0 * DIN * DINT, al1 + g0 * 128, ar1 + g0 * 128,
            projg, elg, erg, N2, N1);
        k_agg_grp<<<N2 / 4, 256, 0, stream>>>(
            projg, src_idx1 + (size_t)g0 * N2 * KNB, elg, erg,
            acc, N2, N1, gsz, g == 0);
    }

    // ---------------- root gather (+ bias + relu(x/R)) ----------------
    k_root<<<(N2 * DIN) / 256, 256, 0, stream>>>(acc, root, bsum + 128, out, N2 * DIN);
}